// Round 2
// baseline (3621.314 us; speedup 1.0000x reference)
//
#include <hip/hip_runtime.h>

typedef unsigned short u16;
typedef __attribute__((ext_vector_type(4))) float v4f;
typedef __attribute__((ext_vector_type(8))) short bf16x8;

#define B_ 8
#define T_ 2048
#define D_ 1024
#define NH_ 8
#define DH_ 128
#define H_ 1024
#define P_ 1365
#define PPAD_ 1408   // P padded to multiple of 128 (up-GEMM N, down-GEMM K)
#define M_ 16384     // B*T

// ---------- bf16 helpers (manual RNE) ---------------------------------------
__device__ __forceinline__ u16 f2b(float f) {
    union { float f; unsigned u; } v; v.f = f;
    unsigned r = (v.u + 0x7fffu + ((v.u >> 16) & 1u)) >> 16;
    return (u16)r;
}
__device__ __forceinline__ float b2f(u16 u) {
    union { unsigned u; float f; } v; v.u = ((unsigned)u) << 16;
    return v.f;
}

// async global->LDS, 16B per lane; lds ptr must be wave-uniform
#define GLD16(gp, lp) __builtin_amdgcn_global_load_lds( \
    (const __attribute__((address_space(1))) void*)(gp), \
    (__attribute__((address_space(3))) void*)(lp), 16, 0, 0)

// ---------------- transpose + cast fp32 -> bf16 ------------------------------
// in: (K x N) fp32 with row stride ldin; out: (Npad x Kpad) bf16, zero-padded
__global__ __launch_bounds__(256) void transpose_cast(
    const float* __restrict__ in, u16* __restrict__ out,
    int K, int N, int Kpad, int Npad, int ldin)
{
    __shared__ float tile[32][33];
    const int tx = threadIdx.x, ty = threadIdx.y;
    const int nblk = blockIdx.x * 32, kblk = blockIdx.y * 32;
#pragma unroll
    for (int i = 0; i < 4; ++i) {
        int k = kblk + ty + i * 8, n = nblk + tx;
        float v = (k < K && n < N) ? in[(size_t)k * ldin + n] : 0.f;
        tile[ty + i * 8][tx] = v;
    }
    __syncthreads();
#pragma unroll
    for (int i = 0; i < 4; ++i) {
        int n = nblk + ty + i * 8, k = kblk + tx;
        if (n < Npad && k < Kpad) out[(size_t)n * Kpad + k] = f2b(tile[tx][ty + i * 8]);
    }
}

// ---------------- concat gate biases ----------------------------------------
__global__ __launch_bounds__(256) void bias4_concat(
    const float* __restrict__ bz, const float* __restrict__ bi,
    const float* __restrict__ bo, const float* __restrict__ bf,
    float* __restrict__ b4)
{
    int j = blockIdx.x * 256 + threadIdx.x;  // 0..4095
    const float* p = (j < 1024) ? bz : (j < 2048) ? bi : (j < 3072) ? bo : bf;
    b4[j] = p[j & 1023];
}

// ---------------- LayerNorm over D=1024 + cast to bf16 ----------------------
__global__ __launch_bounds__(256) void ln_cast_kernel(
    const float* __restrict__ x, const float* __restrict__ w,
    const float* __restrict__ b, u16* __restrict__ xnb)
{
    const int token = blockIdx.x, tid = threadIdx.x;
    const float4* xr = (const float4*)(x + (size_t)token * D_);
    float4 v = xr[tid];
    float s  = v.x + v.y + v.z + v.w;
    float ss = v.x * v.x + v.y * v.y + v.z * v.z + v.w * v.w;
    for (int off = 32; off; off >>= 1) { s += __shfl_down(s, off); ss += __shfl_down(ss, off); }
    __shared__ float wsum[4], wsq[4], stats[2];
    const int wave = tid >> 6, lane = tid & 63;
    if (lane == 0) { wsum[wave] = s; wsq[wave] = ss; }
    __syncthreads();
    if (tid == 0) {
        float S = 0.f, SS = 0.f;
        for (int i = 0; i < 4; ++i) { S += wsum[i]; SS += wsq[i]; }
        float mu = S * (1.f / 1024.f);
        float var = SS * (1.f / 1024.f) - mu * mu;
        stats[0] = mu; stats[1] = rsqrtf(var + 1e-6f);
    }
    __syncthreads();
    const float mu = stats[0], rs = stats[1];
    float4 wv = ((const float4*)w)[tid];
    float4 bv = ((const float4*)b)[tid];
    ushort4 o;
    o.x = f2b((v.x - mu) * rs * wv.x + bv.x);
    o.y = f2b((v.y - mu) * rs * wv.y + bv.y);
    o.z = f2b((v.z - mu) * rs * wv.z + bv.z);
    o.w = f2b((v.w - mu) * rs * wv.w + bv.w);
    ((ushort4*)(xnb + (size_t)token * D_))[tid] = o;
}

// ---------------- m97-style bf16 MFMA GEMM core (128x128 tile, BK=32) -------
__device__ __forceinline__ void gemm128_core(
    const u16* __restrict__ A, const u16* __restrict__ BT,
    int K, int m0, int n0, v4f acc[4][4])
{
    __shared__ __align__(16) u16 As[4096];  // [128][32]
    __shared__ __align__(16) u16 Bs[4096];  // [128][32]
    const int tid = threadIdx.x;
    const int wave = tid >> 6, lane = tid & 63;
    const int wm = wave & 1, wn = wave >> 1;
    const int srow = tid >> 2, sseg = tid & 3;
    const int lm = lane & 15, lq = lane >> 4;

    const u16* gA0 = A  + (size_t)(m0 + srow) * K + sseg * 8;
    const u16* gA1 = gA0 + (size_t)64 * K;
    const u16* gB0 = BT + (size_t)(n0 + srow) * K + sseg * 8;
    const u16* gB1 = gB0 + (size_t)64 * K;
    u16* lA0 = As + wave * 512;
    u16* lA1 = As + 2048 + wave * 512;
    u16* lB0 = Bs + wave * 512;
    u16* lB1 = Bs + 2048 + wave * 512;

    for (int kk = 0; kk < K; kk += 32) {
        GLD16(gA0 + kk, lA0);
        GLD16(gA1 + kk, lA1);
        GLD16(gB0 + kk, lB0);
        GLD16(gB1 + kk, lB1);
        __syncthreads();
        bf16x8 a[4], b[4];
#pragma unroll
        for (int i = 0; i < 4; ++i) {
            a[i] = *(const bf16x8*)(As + (wm * 64 + i * 16 + lm) * 32 + lq * 8);
            b[i] = *(const bf16x8*)(Bs + (wn * 64 + i * 16 + lm) * 32 + lq * 8);
        }
#pragma unroll
        for (int i = 0; i < 4; ++i)
#pragma unroll
            for (int j = 0; j < 4; ++j)
                acc[i][j] = __builtin_amdgcn_mfma_f32_16x16x32_bf16(a[i], b[j], acc[i][j], 0, 0, 0);
        __syncthreads();
    }
}

// ---------------- fused 4-gate GEMM (N=4096) for one T-chunk ----------------
// A: xnb [M][D] (token order b*T+t). C: gx chunk [4][B][Tc][H] bf16.
__global__ __launch_bounds__(256) void gemm_gate4(
    const u16* __restrict__ A, const u16* __restrict__ WT4,
    const float* __restrict__ bias4, u16* __restrict__ gxc,
    int t0, int Tc)
{
    v4f acc[4][4];
#pragma unroll
    for (int i = 0; i < 4; ++i)
#pragma unroll
        for (int j = 0; j < 4; ++j)
#pragma unroll
            for (int r = 0; r < 4; ++r) acc[i][j][r] = 0.f;
    const int mtPerB = Tc >> 7;
    const int b_ = blockIdx.y / mtPerB, tt = blockIdx.y % mtPerB;
    const int m0 = b_ * T_ + t0 + tt * 128;
    const int n0 = blockIdx.x * 128;
    gemm128_core(A, WT4, D_, m0, n0, acc);
    const int g = n0 >> 10, nh0 = n0 & 1023;
    const int c0 = (g * B_ + b_) * Tc + tt * 128;
    const int tid = threadIdx.x, wave = tid >> 6, lane = tid & 63;
    const int wm = wave & 1, wn = wave >> 1;
    const int col = lane & 15, rb0 = (lane >> 4) * 4;
#pragma unroll
    for (int j = 0; j < 4; ++j) {
        const int nh = nh0 + wn * 64 + j * 16 + col;
        const float bv = bias4[n0 + wn * 64 + j * 16 + col];
#pragma unroll
        for (int i = 0; i < 4; ++i)
#pragma unroll
            for (int r = 0; r < 4; ++r) {
                const int rr = c0 + wm * 64 + i * 16 + rb0 + r;
                gxc[(size_t)rr * H_ + nh] = f2b(acc[i][j][r] + bv);
            }
    }
}

// ---------------- sequential scan + fused multihead-LN ----------------------
// One WG per (batch, head). 512 thr: tid = g*128 + e. Rcol in VGPRs, h in LDS.
__global__ __launch_bounds__(512) void scan_kernel(
    const u16* __restrict__ gxc,  // [4][B][Tc][H] bf16 (bias included)
    const float* __restrict__ Rz, const float* __restrict__ rbz,
    const float* __restrict__ Ri, const float* __restrict__ rbi,
    const float* __restrict__ Ro, const float* __restrict__ rbo,
    const float* __restrict__ Rf, const float* __restrict__ rbf,
    const float* __restrict__ hlnw, const float* __restrict__ hlnb,
    float* __restrict__ state,    // [64][4][128] c,n,m,h
    u16* __restrict__ hbn,        // [M][H] bf16 (mLN output)
    int t0, int Tc, int init)
{
    const int blk = blockIdx.x;           // 0..63
    const int b = blk >> 3, hd = blk & 7;
    const int tid = threadIdx.x;
    const int g = tid >> 7, e = tid & 127;
    const int wave = tid >> 6, lane = tid & 63;

    const float* Rg  = (g == 0) ? Rz : (g == 1) ? Ri : (g == 2) ? Ro : Rf;
    const float* rbg = (g == 0) ? rbz : (g == 1) ? rbi : (g == 2) ? rbo : rbf;

    float Rcol[128];
#pragma unroll
    for (int d = 0; d < 128; ++d)
        Rcol[d] = Rg[(size_t)hd * (DH_ * DH_) + d * DH_ + e];
    const float rb = rbg[hd * DH_ + e];
    float lw = 0.f, lb = 0.f;
    if (tid < 128) { lw = hlnw[hd * DH_ + tid]; lb = hlnb[hd * DH_ + tid]; }

    __shared__ __align__(16) float h_lds[128];
    __shared__ float actv[4][128];
    __shared__ float red[2][2];
    float* st = state + (size_t)blk * 4 * 128;
    float c = 0.f, nst = 1.f, mst = 0.f, hcur = 0.f;
    if (!init && tid < 128) {
        c = st[tid]; nst = st[128 + tid]; mst = st[256 + tid]; hcur = st[384 + tid];
    }
    if (tid < 128) h_lds[tid] = hcur;
    __syncthreads();

    const u16* gxg = gxc + ((size_t)(g * B_ + b) * Tc) * H_ + hd * DH_ + e;
    float gv = b2f(gxg[0]);

    for (int tl = 0; tl < Tc; ++tl) {
        float gvn = (tl + 1 < Tc) ? b2f(gxg[(size_t)(tl + 1) * H_]) : 0.f;
        float d0 = 0.f, d1 = 0.f, d2 = 0.f, d3 = 0.f;
        const float4* h4 = (const float4*)h_lds;
#pragma unroll
        for (int q = 0; q < 32; ++q) {
            float4 hv = h4[q];
            d0 = fmaf(Rcol[4 * q + 0], hv.x, d0);
            d1 = fmaf(Rcol[4 * q + 1], hv.y, d1);
            d2 = fmaf(Rcol[4 * q + 2], hv.z, d2);
            d3 = fmaf(Rcol[4 * q + 3], hv.w, d3);
        }
        const float pre = gv + rb + (d0 + d1) + (d2 + d3);
        float act;
        if (g == 0)      act = tanhf(pre);                       // z
        else if (g == 2) act = 1.f / (1.f + __expf(-pre));       // o
        else             act = 15.f * tanhf(pre * (1.f / 15.f)); // i,f softcap
        actv[g][e] = act;
        __syncthreads();
        if (tid < 128) {
            const float zv = actv[0][tid], ip = actv[1][tid];
            const float ov = actv[2][tid], fp = actv[3][tid];
            const float mt = fmaxf(fp + mst, ip);
            const float ig = __expf(ip - mt);
            const float fg = __expf(fp - mt + mst);
            c   = fg * c + ig * zv;
            nst = fg * nst + ig;
            mst = mt;
            hcur = ov * (c / fmaxf(nst, 1.f));
            h_lds[tid] = hcur;
            float s = hcur, ss = hcur * hcur;
            for (int off = 32; off; off >>= 1) {
                s += __shfl_xor(s, off); ss += __shfl_xor(ss, off);
            }
            if (lane == 0) { red[wave][0] = s; red[wave][1] = ss; }
        }
        __syncthreads();
        if (tid < 128) {
            const float S = red[0][0] + red[1][0], SS = red[0][1] + red[1][1];
            const float mu = S * (1.f / 128.f);
            const float var = SS * (1.f / 128.f) - mu * mu;
            const float rs = rsqrtf(var + 1e-6f);
            const int t = t0 + tl;
            hbn[(size_t)(b * T_ + t) * H_ + hd * DH_ + tid] =
                f2b((hcur - mu) * rs * lw + lb);
        }
        gv = gvn;
    }
    if (tid < 128) {
        st[tid] = c; st[128 + tid] = nst; st[256 + tid] = mst; st[384 + tid] = hcur;
    }
}

// ---------------- up-GEMM with fused GEGLU ----------------------------------
// u1 tile = A·W1T, u2 tile = A·W2T (same n0), write g = u1*gelu(u2) directly.
__global__ __launch_bounds__(256) void gemm_up_geglu(
    const u16* __restrict__ A, const u16* __restrict__ B1T,
    const u16* __restrict__ B2T, const float* __restrict__ upb,
    u16* __restrict__ G)
{
    __shared__ __align__(16) u16 As[4096], B1s[4096], B2s[4096];
    v4f acc1[4][4], acc2[4][4];
#pragma unroll
    for (int i = 0; i < 4; ++i)
#pragma unroll
        for (int j = 0; j < 4; ++j)
#pragma unroll
            for (int r = 0; r < 4; ++r) { acc1[i][j][r] = 0.f; acc2[i][j][r] = 0.f; }
    const int m0 = blockIdx.y * 128, n0 = blockIdx.x * 128;
    const int tid = threadIdx.x;
    const int wave = tid >> 6, lane = tid & 63;
    const int wm = wave & 1, wn = wave >> 1;
    const int srow = tid >> 2, sseg = tid & 3;
    const int lm = lane & 15, lq = lane >> 4;

    const u16* gA0 = A   + (size_t)(m0 + srow) * H_ + sseg * 8;
    const u16* gA1 = gA0 + (size_t)64 * H_;
    const u16* g10 = B1T + (size_t)(n0 + srow) * H_ + sseg * 8;
    const u16* g11 = g10 + (size_t)64 * H_;
    const u16* g20 = B2T + (size_t)(n0 + srow) * H_ + sseg * 8;
    const u16* g21 = g20 + (size_t)64 * H_;
    u16* lA0 = As  + wave * 512;        u16* lA1 = As  + 2048 + wave * 512;
    u16* l10 = B1s + wave * 512;        u16* l11 = B1s + 2048 + wave * 512;
    u16* l20 = B2s + wave * 512;        u16* l21 = B2s + 2048 + wave * 512;

    for (int kk = 0; kk < H_; kk += 32) {
        GLD16(gA0 + kk, lA0); GLD16(gA1 + kk, lA1);
        GLD16(g10 + kk, l10); GLD16(g11 + kk, l11);
        GLD16(g20 + kk, l20); GLD16(g21 + kk, l21);
        __syncthreads();
        bf16x8 a[4], b1[4], b2[4];
#pragma unroll
        for (int i = 0; i < 4; ++i) {
            a[i]  = *(const bf16x8*)(As  + (wm * 64 + i * 16 + lm) * 32 + lq * 8);
            b1[i] = *(const bf16x8*)(B1s + (wn * 64 + i * 16 + lm) * 32 + lq * 8);
            b2[i] = *(const bf16x8*)(B2s + (wn * 64 + i * 16 + lm) * 32 + lq * 8);
        }
#pragma unroll
        for (int i = 0; i < 4; ++i)
#pragma unroll
            for (int j = 0; j < 4; ++j) {
                acc1[i][j] = __builtin_amdgcn_mfma_f32_16x16x32_bf16(a[i], b1[j], acc1[i][j], 0, 0, 0);
                acc2[i][j] = __builtin_amdgcn_mfma_f32_16x16x32_bf16(a[i], b2[j], acc2[i][j], 0, 0, 0);
            }
        __syncthreads();
    }
    const int col = lane & 15, rb0 = (lane >> 4) * 4;
#pragma unroll
    for (int j = 0; j < 4; ++j) {
        const int n = n0 + wn * 64 + j * 16 + col;
        const bool ok = (n < P_);
        const float bb1 = ok ? upb[n] : 0.f;
        const float bb2 = ok ? upb[P_ + n] : 0.f;
#pragma unroll
        for (int i = 0; i < 4; ++i)
#pragma unroll
            for (int r = 0; r < 4; ++r) {
                const int mm = m0 + wm * 64 + i * 16 + rb0 + r;
                float gval = 0.f;
                if (ok) {
                    const float u1 = acc1[i][j][r] + bb1;
                    const float u2 = acc2[i][j][r] + bb2;
                    const float ge = 0.5f * u2 * (1.f + erff(u2 * 0.70710678118654752f));
                    gval = u1 * ge;
                }
                G[(size_t)mm * PPAD_ + n] = f2b(gval);
            }
    }
}

// ---------------- down GEMM -> fp32 out with bias + residual ----------------
__global__ __launch_bounds__(256) void gemm_down_out(
    const u16* __restrict__ A, const u16* __restrict__ BT,
    const float* __restrict__ bias, const float* __restrict__ resid,
    float* __restrict__ C, int K, int ldc)
{
    v4f acc[4][4];
#pragma unroll
    for (int i = 0; i < 4; ++i)
#pragma unroll
        for (int j = 0; j < 4; ++j)
#pragma unroll
            for (int r = 0; r < 4; ++r) acc[i][j][r] = 0.f;
    const int m0 = blockIdx.y * 128, n0 = blockIdx.x * 128;
    gemm128_core(A, BT, K, m0, n0, acc);
    const int tid = threadIdx.x, wave = tid >> 6, lane = tid & 63;
    const int wm = wave & 1, wn = wave >> 1;
    const int col = lane & 15, rb0 = (lane >> 4) * 4;
#pragma unroll
    for (int j = 0; j < 4; ++j) {
        const int n = n0 + wn * 64 + j * 16 + col;
        const float bv = bias[n];
#pragma unroll
        for (int i = 0; i < 4; ++i)
#pragma unroll
            for (int r = 0; r < 4; ++r) {
                const int mm = m0 + wm * 64 + i * 16 + rb0 + r;
                C[(size_t)mm * ldc + n] = acc[i][j][r] + bv + resid[(size_t)mm * ldc + n];
            }
    }
}

// ============================ launcher ======================================
extern "C" void kernel_launch(void* const* d_in, const int* in_sizes, int n_in,
                              void* d_out, int out_size, void* d_ws, size_t ws_size,
                              hipStream_t stream)
{
    const float* x     = (const float*)d_in[0];
    const float* ln_w  = (const float*)d_in[1];
    const float* ln_b  = (const float*)d_in[2];
    const float* hln_w = (const float*)d_in[3];
    const float* hln_b = (const float*)d_in[4];
    const float* Wz = (const float*)d_in[5];  const float* bz  = (const float*)d_in[6];
    const float* Wi = (const float*)d_in[7];  const float* bi  = (const float*)d_in[8];
    const float* Wo = (const float*)d_in[9];  const float* bo  = (const float*)d_in[10];
    const float* Wf = (const float*)d_in[11]; const float* bfv = (const float*)d_in[12];
    const float* Rz = (const float*)d_in[13]; const float* rbz = (const float*)d_in[14];
    const float* Ri = (const float*)d_in[15]; const float* rbi = (const float*)d_in[16];
    const float* Ro = (const float*)d_in[17]; const float* rbo = (const float*)d_in[18];
    const float* Rf = (const float*)d_in[19]; const float* rbf = (const float*)d_in[20];
    const float* up_w   = (const float*)d_in[21]; const float* up_b   = (const float*)d_in[22];
    const float* down_w = (const float*)d_in[23]; const float* down_b = (const float*)d_in[24];
    float* out = (float*)d_out;

    // ---- workspace layout (adaptive to ws_size) ----
    size_t off = 0;
    char* base = (char*)d_ws;
    auto alloc = [&](size_t bytes) -> char* {
        char* r = base + off; off += (bytes + 255) & ~(size_t)255; return r;
    };
    u16*   WT4   = (u16*)  alloc((size_t)4 * H_ * D_ * 2);      // 8 MiB
    u16*   W1T   = (u16*)  alloc((size_t)PPAD_ * H_ * 2);       // 2.75 MiB
    u16*   W2T   = (u16*)  alloc((size_t)PPAD_ * H_ * 2);       // 2.75 MiB
    u16*   dnT   = (u16*)  alloc((size_t)D_ * PPAD_ * 2);       // 2.75 MiB
    float* bias4 = (float*)alloc(4096 * 4);
    float* state = (float*)alloc((size_t)64 * 4 * 128 * 4);     // 128 KiB
    u16*   hbn   = (u16*)  alloc((size_t)M_ * H_ * 2);          // 32 MiB
    char*  dyn   = base + off;
    u16*   xnb   = (u16*)dyn;                                   // 32 MiB
    const size_t xnb_bytes = (size_t)M_ * H_ * 2;
    u16*   gbuf  = (u16*)dyn;  // overlays xnb+gx (both dead by up-GEMM time)

    // pick largest Tc whose gx chunk fits
    const size_t fixed = off + xnb_bytes;
    int Tc = 256;
    if      (ws_size >= fixed + (size_t)4 * B_ * 2048 * H_ * 2) Tc = 2048;
    else if (ws_size >= fixed + (size_t)4 * B_ * 1024 * H_ * 2) Tc = 1024;
    else if (ws_size >= fixed + (size_t)4 * B_ * 512  * H_ * 2) Tc = 512;
    u16* gx = (u16*)(dyn + xnb_bytes);
    const int NC = T_ / Tc;

    // ---- weight prep ----
    dim3 tb(32, 8);
    const float* Ws[4] = {Wz, Wi, Wo, Wf};
    for (int g = 0; g < 4; ++g)
        transpose_cast<<<dim3(32, 32), tb, 0, stream>>>(
            Ws[g], WT4 + (size_t)g * H_ * D_, D_, H_, D_, H_, H_);
    transpose_cast<<<dim3(44, 32), tb, 0, stream>>>(up_w,      W1T, H_, P_, H_, PPAD_, 2 * P_);
    transpose_cast<<<dim3(44, 32), tb, 0, stream>>>(up_w + P_, W2T, H_, P_, H_, PPAD_, 2 * P_);
    transpose_cast<<<dim3(32, 44), tb, 0, stream>>>(down_w, dnT, P_, D_, PPAD_, D_, D_);
    bias4_concat<<<16, 256, 0, stream>>>(bz, bi, bo, bfv, bias4);

    // ---- input LN ----
    ln_cast_kernel<<<M_, 256, 0, stream>>>(x, ln_w, ln_b, xnb);

    // ---- chunked gate GEMM + scan ----
    for (int cidx = 0; cidx < NC; ++cidx) {
        const int t0 = cidx * Tc;
        gemm_gate4<<<dim3(32, B_ * (Tc / 128)), 256, 0, stream>>>(
            xnb, WT4, bias4, gx, t0, Tc);
        scan_kernel<<<64, 512, 0, stream>>>(
            gx, Rz, rbz, Ri, rbi, Ro, rbo, Rf, rbf, hln_w, hln_b,
            state, hbn, t0, Tc, cidx == 0 ? 1 : 0);
    }

    // ---- FFN ----
    gemm_up_geglu<<<dim3(PPAD_ / 128, 128), 256, 0, stream>>>(hbn, W1T, W2T, up_b, gbuf);
    gemm_down_out<<<dim3(8, 128), 256, 0, stream>>>(gbuf, dnT, down_b, x, out, PPAD_, D_);

    (void)in_sizes; (void)n_in; (void)out_size;
}

// Round 3
// 2575.500 us; speedup vs baseline: 1.4061x; 1.4061x over previous
//
#include <hip/hip_runtime.h>

typedef unsigned short u16;
typedef __attribute__((ext_vector_type(4))) float v4f;
typedef __attribute__((ext_vector_type(8))) short bf16x8;

#define B_ 8
#define T_ 2048
#define D_ 1024
#define NH_ 8
#define DH_ 128
#define H_ 1024
#define P_ 1365
#define PPAD_ 1408   // P padded to multiple of 128 (up-GEMM N, down-GEMM K)
#define M_ 16384     // B*T

// ---------- bf16 helpers (manual RNE) ---------------------------------------
__device__ __forceinline__ u16 f2b(float f) {
    union { float f; unsigned u; } v; v.f = f;
    unsigned r = (v.u + 0x7fffu + ((v.u >> 16) & 1u)) >> 16;
    return (u16)r;
}
__device__ __forceinline__ float b2f(u16 u) {
    union { unsigned u; float f; } v; v.u = ((unsigned)u) << 16;
    return v.f;
}

// async global->LDS, 16B per lane; lds ptr must be wave-uniform
#define GLD16(gp, lp) __builtin_amdgcn_global_load_lds( \
    (const __attribute__((address_space(1))) void*)(gp), \
    (__attribute__((address_space(3))) void*)(lp), 16, 0, 0)

// ---------------- transpose + cast fp32 -> bf16 ------------------------------
__global__ __launch_bounds__(256) void transpose_cast(
    const float* __restrict__ in, u16* __restrict__ out,
    int K, int N, int Kpad, int Npad, int ldin)
{
    __shared__ float tile[32][33];
    const int tx = threadIdx.x, ty = threadIdx.y;
    const int nblk = blockIdx.x * 32, kblk = blockIdx.y * 32;
#pragma unroll
    for (int i = 0; i < 4; ++i) {
        int k = kblk + ty + i * 8, n = nblk + tx;
        float v = (k < K && n < N) ? in[(size_t)k * ldin + n] : 0.f;
        tile[ty + i * 8][tx] = v;
    }
    __syncthreads();
#pragma unroll
    for (int i = 0; i < 4; ++i) {
        int n = nblk + ty + i * 8, k = kblk + tx;
        if (n < Npad && k < Kpad) out[(size_t)n * Kpad + k] = f2b(tile[tx][ty + i * 8]);
    }
}

// ---------------- concat 4 per-gate vectors [1024] -> [4][1024] --------------
__global__ __launch_bounds__(256) void bias4_concat(
    const float* __restrict__ bz, const float* __restrict__ bi,
    const float* __restrict__ bo, const float* __restrict__ bf,
    float* __restrict__ b4)
{
    int j = blockIdx.x * 256 + threadIdx.x;  // 0..4095
    const float* p = (j < 1024) ? bz : (j < 2048) ? bi : (j < 3072) ? bo : bf;
    b4[j] = p[j & 1023];
}

// ---------------- pack R into MFMA A-layout: RQ[hd][m=e*4+g][d] bf16 --------
__global__ __launch_bounds__(128) void rq_prep(
    const float* __restrict__ Rz, const float* __restrict__ Ri,
    const float* __restrict__ Ro, const float* __restrict__ Rf,
    u16* __restrict__ RQ)
{
    const int m = blockIdx.x;      // 0..511
    const int hd = blockIdx.y;     // 0..7
    const int d = threadIdx.x;     // 0..127
    const int g = m & 3, e = m >> 2;
    const float* Rg = (g == 0) ? Rz : (g == 1) ? Ri : (g == 2) ? Ro : Rf;
    RQ[((size_t)hd * 512 + m) * 128 + d] =
        f2b(Rg[((size_t)hd * 128 + d) * 128 + e]);
}

// ---------------- LayerNorm over D=1024 + cast to bf16 ----------------------
__global__ __launch_bounds__(256) void ln_cast_kernel(
    const float* __restrict__ x, const float* __restrict__ w,
    const float* __restrict__ b, u16* __restrict__ xnb)
{
    const int token = blockIdx.x, tid = threadIdx.x;
    const float4* xr = (const float4*)(x + (size_t)token * D_);
    float4 v = xr[tid];
    float s  = v.x + v.y + v.z + v.w;
    float ss = v.x * v.x + v.y * v.y + v.z * v.z + v.w * v.w;
    for (int off = 32; off; off >>= 1) { s += __shfl_down(s, off); ss += __shfl_down(ss, off); }
    __shared__ float wsum[4], wsq[4], stats[2];
    const int wave = tid >> 6, lane = tid & 63;
    if (lane == 0) { wsum[wave] = s; wsq[wave] = ss; }
    __syncthreads();
    if (tid == 0) {
        float S = 0.f, SS = 0.f;
        for (int i = 0; i < 4; ++i) { S += wsum[i]; SS += wsq[i]; }
        float mu = S * (1.f / 1024.f);
        float var = SS * (1.f / 1024.f) - mu * mu;
        stats[0] = mu; stats[1] = rsqrtf(var + 1e-6f);
    }
    __syncthreads();
    const float mu = stats[0], rs = stats[1];
    float4 wv = ((const float4*)w)[tid];
    float4 bv = ((const float4*)b)[tid];
    ushort4 o;
    o.x = f2b((v.x - mu) * rs * wv.x + bv.x);
    o.y = f2b((v.y - mu) * rs * wv.y + bv.y);
    o.z = f2b((v.z - mu) * rs * wv.z + bv.z);
    o.w = f2b((v.w - mu) * rs * wv.w + bv.w);
    ((ushort4*)(xnb + (size_t)token * D_))[tid] = o;
}

// ---------------- m97-style bf16 MFMA GEMM core (128x128 tile, BK=32) -------
__device__ __forceinline__ void gemm128_core(
    const u16* __restrict__ A, const u16* __restrict__ BT,
    int K, int m0, int n0, v4f acc[4][4])
{
    __shared__ __align__(16) u16 As[4096];  // [128][32]
    __shared__ __align__(16) u16 Bs[4096];  // [128][32]
    const int tid = threadIdx.x;
    const int wave = tid >> 6, lane = tid & 63;
    const int wm = wave & 1, wn = wave >> 1;
    const int srow = tid >> 2, sseg = tid & 3;
    const int lm = lane & 15, lq = lane >> 4;

    const u16* gA0 = A  + (size_t)(m0 + srow) * K + sseg * 8;
    const u16* gA1 = gA0 + (size_t)64 * K;
    const u16* gB0 = BT + (size_t)(n0 + srow) * K + sseg * 8;
    const u16* gB1 = gB0 + (size_t)64 * K;
    u16* lA0 = As + wave * 512;
    u16* lA1 = As + 2048 + wave * 512;
    u16* lB0 = Bs + wave * 512;
    u16* lB1 = Bs + 2048 + wave * 512;

    for (int kk = 0; kk < K; kk += 32) {
        GLD16(gA0 + kk, lA0);
        GLD16(gA1 + kk, lA1);
        GLD16(gB0 + kk, lB0);
        GLD16(gB1 + kk, lB1);
        __syncthreads();
        bf16x8 a[4], b[4];
#pragma unroll
        for (int i = 0; i < 4; ++i) {
            a[i] = *(const bf16x8*)(As + (wm * 64 + i * 16 + lm) * 32 + lq * 8);
            b[i] = *(const bf16x8*)(Bs + (wn * 64 + i * 16 + lm) * 32 + lq * 8);
        }
#pragma unroll
        for (int i = 0; i < 4; ++i)
#pragma unroll
            for (int j = 0; j < 4; ++j)
                acc[i][j] = __builtin_amdgcn_mfma_f32_16x16x32_bf16(a[i], b[j], acc[i][j], 0, 0, 0);
        __syncthreads();
    }
}

// ---------------- fused 4-gate GEMM (N=4096) for one T-chunk ----------------
__global__ __launch_bounds__(256) void gemm_gate4(
    const u16* __restrict__ A, const u16* __restrict__ WT4,
    const float* __restrict__ bias4, u16* __restrict__ gxc,
    int t0, int Tc)
{
    v4f acc[4][4];
#pragma unroll
    for (int i = 0; i < 4; ++i)
#pragma unroll
        for (int j = 0; j < 4; ++j)
#pragma unroll
            for (int r = 0; r < 4; ++r) acc[i][j][r] = 0.f;
    const int mtPerB = Tc >> 7;
    const int b_ = blockIdx.y / mtPerB, tt = blockIdx.y % mtPerB;
    const int m0 = b_ * T_ + t0 + tt * 128;
    const int n0 = blockIdx.x * 128;
    gemm128_core(A, WT4, D_, m0, n0, acc);
    const int g = n0 >> 10, nh0 = n0 & 1023;
    const int c0 = (g * B_ + b_) * Tc + tt * 128;
    const int tid = threadIdx.x, wave = tid >> 6, lane = tid & 63;
    const int wm = wave & 1, wn = wave >> 1;
    const int col = lane & 15, rb0 = (lane >> 4) * 4;
#pragma unroll
    for (int j = 0; j < 4; ++j) {
        const int nh = nh0 + wn * 64 + j * 16 + col;
        const float bv = bias4[n0 + wn * 64 + j * 16 + col];
#pragma unroll
        for (int i = 0; i < 4; ++i)
#pragma unroll
            for (int r = 0; r < 4; ++r) {
                const int rr = c0 + wm * 64 + i * 16 + rb0 + r;
                gxc[(size_t)rr * H_ + nh] = f2b(acc[i][j][r] + bv);
            }
    }
}

// ---------------- MFMA sequential scan --------------------------------------
// One WG per (batch, head). 512 thr = 8 waves. Matvec out[m=4e+g] = RQ·h via
// MFMA 16x16x32 (N-col 0 = real data). Updaters (tid<128) do gates+state.
__global__ __launch_bounds__(512, 1) void scan_kernel(
    const u16* __restrict__ gxc,  // [4][B][Tc][H] bf16 (Wx+b preacts)
    const u16* __restrict__ RQ,   // [8][512][128] bf16, rows m=e*4+g
    const float* __restrict__ rb4,// [4][H] recurrent biases
    float* __restrict__ state,    // [64][4][128] c,n,m,h
    u16* __restrict__ hraw,       // [M][H] bf16 raw h
    int t0, int Tc, int init)
{
    const int blk = blockIdx.x;           // 0..63
    const int b = blk >> 3, hd = blk & 7;
    const int tid = threadIdx.x;
    const int w = tid >> 6, lane = tid & 63;
    const int lrow = lane & 15, lsec = lane >> 4;

    __shared__ __align__(16) u16 hB[16 * 136];   // B-operand tile [col][k], pad 8
    __shared__ __align__(16) float Cbuf[512];    // matvec out, m = 4e+g

    // preload A fragments: wave w owns rows 64w..64w+63 (4 tiles x 4 K-chunks)
    bf16x8 a[4][4];
    const u16* RQh = RQ + (size_t)hd * 512 * 128;
#pragma unroll
    for (int i = 0; i < 4; ++i)
#pragma unroll
        for (int kc = 0; kc < 4; ++kc)
            a[i][kc] = *(const bf16x8*)(RQh +
                (size_t)(w * 64 + i * 16 + lrow) * 128 + kc * 32 + lsec * 8);

    // zero B tile (garbage cols must be finite)
    for (int j = tid; j < 16 * 136 / 2; j += 512) ((unsigned*)hB)[j] = 0u;

    float c = 0.f, nst = 1.f, mst = 0.f, hcur = 0.f;
    float rbz_ = 0.f, rbi_ = 0.f, rbo_ = 0.f, rbf_ = 0.f;
    if (tid < 128) {
        rbz_ = rb4[0 * H_ + hd * 128 + tid];
        rbi_ = rb4[1 * H_ + hd * 128 + tid];
        rbo_ = rb4[2 * H_ + hd * 128 + tid];
        rbf_ = rb4[3 * H_ + hd * 128 + tid];
        if (!init) {
            const float* st = state + (size_t)blk * 512;
            c = st[tid]; nst = st[128 + tid]; mst = st[256 + tid]; hcur = st[384 + tid];
        }
    }
    __syncthreads();
    if (tid < 128) hB[tid] = f2b(hcur);   // col 0 row
    __syncthreads();

    const u16* gxb = gxc + (size_t)b * Tc * H_ + hd * 128;  // g=0 plane
    const size_t gstride = (size_t)B_ * Tc * H_;
    u16* hout = hraw + (size_t)(b * T_ + t0) * H_ + hd * 128;

    for (int tl = 0; tl < Tc; ++tl) {
        // gate-GEMM preacts for this step (latency hidden by MFMA phase)
        float g0 = 0.f, g1 = 0.f, g2 = 0.f, g3 = 0.f;
        if (tid < 128) {
            const u16* gp = gxb + (size_t)tl * H_ + tid;
            g0 = b2f(gp[0]);
            g1 = b2f(gp[gstride]);
            g2 = b2f(gp[2 * gstride]);
            g3 = b2f(gp[3 * gstride]);
        }
        v4f acc[4];
#pragma unroll
        for (int i = 0; i < 4; ++i)
#pragma unroll
            for (int r = 0; r < 4; ++r) acc[i][r] = 0.f;
#pragma unroll
        for (int kc = 0; kc < 4; ++kc) {
            bf16x8 bf = *(const bf16x8*)(hB + lrow * 136 + kc * 32 + lsec * 8);
#pragma unroll
            for (int i = 0; i < 4; ++i)
                acc[i] = __builtin_amdgcn_mfma_f32_16x16x32_bf16(a[i][kc], bf, acc[i], 0, 0, 0);
        }
        if (lrow == 0) {   // col-0 holder lanes: rows 64w+16i+4*lsec+r
#pragma unroll
            for (int i = 0; i < 4; ++i)
                *(v4f*)(Cbuf + w * 64 + i * 16 + lsec * 4) = acc[i];
        }
        __syncthreads();
        if (tid < 128) {
            const float4 pv = *(const float4*)(Cbuf + 4 * tid);  // z,i,o,f matvec
            const float zp   = pv.x + g0 + rbz_;
            const float ipre = 15.f * tanhf((pv.y + g1 + rbi_) * (1.f / 15.f));
            const float op   = pv.z + g2 + rbo_;
            const float fpre = 15.f * tanhf((pv.w + g3 + rbf_) * (1.f / 15.f));
            const float zv = tanhf(zp);
            const float ov = 1.f / (1.f + __expf(-op));
            const float mt = fmaxf(fpre + mst, ipre);
            const float ig = __expf(ipre - mt);
            const float fg = __expf(fpre - mt + mst);
            c   = fg * c + ig * zv;
            nst = fg * nst + ig;
            mst = mt;
            hcur = ov * (c / fmaxf(nst, 1.f));
            const u16 hb16 = f2b(hcur);
            hB[tid] = hb16;
            hout[(size_t)tl * H_ + tid] = hb16;
        }
        __syncthreads();
    }
    if (tid < 128) {
        float* st = state + (size_t)blk * 512;
        st[tid] = c; st[128 + tid] = nst; st[256 + tid] = mst; st[384 + tid] = hcur;
    }
}

// ---------------- multihead layernorm (in-place capable) --------------------
__global__ __launch_bounds__(512) void mln_kernel(
    const u16* __restrict__ h_all, const float* __restrict__ w,
    const float* __restrict__ b, u16* __restrict__ hb)
{
    const int token = blockIdx.x, tid = threadIdx.x;
    const int wave = tid >> 6, lane = tid & 63;
    const u16* hr = h_all + (size_t)token * H_ + wave * DH_;
    float a0 = b2f(hr[lane]), a1 = b2f(hr[64 + lane]);
    float s = a0 + a1, ss = a0 * a0 + a1 * a1;
    for (int off = 32; off; off >>= 1) { s += __shfl_xor(s, off); ss += __shfl_xor(ss, off); }
    const float mu = s * (1.f / 128.f);
    const float var = ss * (1.f / 128.f) - mu * mu;
    const float rs = rsqrtf(var + 1e-6f);
    const int c0 = wave * DH_ + lane;
    u16* hw = hb + (size_t)token * H_ + wave * DH_;
    hw[lane]      = f2b((a0 - mu) * rs * w[c0] + b[c0]);
    hw[64 + lane] = f2b((a1 - mu) * rs * w[c0 + 64] + b[c0 + 64]);
}

// ---------------- up-GEMM with fused GEGLU ----------------------------------
__global__ __launch_bounds__(256) void gemm_up_geglu(
    const u16* __restrict__ A, const u16* __restrict__ B1T,
    const u16* __restrict__ B2T, const float* __restrict__ upb,
    u16* __restrict__ G)
{
    __shared__ __align__(16) u16 As[4096], B1s[4096], B2s[4096];
    v4f acc1[4][4], acc2[4][4];
#pragma unroll
    for (int i = 0; i < 4; ++i)
#pragma unroll
        for (int j = 0; j < 4; ++j)
#pragma unroll
            for (int r = 0; r < 4; ++r) { acc1[i][j][r] = 0.f; acc2[i][j][r] = 0.f; }
    const int m0 = blockIdx.y * 128, n0 = blockIdx.x * 128;
    const int tid = threadIdx.x;
    const int wave = tid >> 6, lane = tid & 63;
    const int wm = wave & 1, wn = wave >> 1;
    const int srow = tid >> 2, sseg = tid & 3;
    const int lm = lane & 15, lq = lane >> 4;

    const u16* gA0 = A   + (size_t)(m0 + srow) * H_ + sseg * 8;
    const u16* gA1 = gA0 + (size_t)64 * H_;
    const u16* g10 = B1T + (size_t)(n0 + srow) * H_ + sseg * 8;
    const u16* g11 = g10 + (size_t)64 * H_;
    const u16* g20 = B2T + (size_t)(n0 + srow) * H_ + sseg * 8;
    const u16* g21 = g20 + (size_t)64 * H_;
    u16* lA0 = As  + wave * 512;        u16* lA1 = As  + 2048 + wave * 512;
    u16* l10 = B1s + wave * 512;        u16* l11 = B1s + 2048 + wave * 512;
    u16* l20 = B2s + wave * 512;        u16* l21 = B2s + 2048 + wave * 512;

    for (int kk = 0; kk < H_; kk += 32) {
        GLD16(gA0 + kk, lA0); GLD16(gA1 + kk, lA1);
        GLD16(g10 + kk, l10); GLD16(g11 + kk, l11);
        GLD16(g20 + kk, l20); GLD16(g21 + kk, l21);
        __syncthreads();
        bf16x8 a[4], b1[4], b2[4];
#pragma unroll
        for (int i = 0; i < 4; ++i) {
            a[i]  = *(const bf16x8*)(As  + (wm * 64 + i * 16 + lm) * 32 + lq * 8);
            b1[i] = *(const bf16x8*)(B1s + (wn * 64 + i * 16 + lm) * 32 + lq * 8);
            b2[i] = *(const bf16x8*)(B2s + (wn * 64 + i * 16 + lm) * 32 + lq * 8);
        }
#pragma unroll
        for (int i = 0; i < 4; ++i)
#pragma unroll
            for (int j = 0; j < 4; ++j) {
                acc1[i][j] = __builtin_amdgcn_mfma_f32_16x16x32_bf16(a[i], b1[j], acc1[i][j], 0, 0, 0);
                acc2[i][j] = __builtin_amdgcn_mfma_f32_16x16x32_bf16(a[i], b2[j], acc2[i][j], 0, 0, 0);
            }
        __syncthreads();
    }
    const int col = lane & 15, rb0 = (lane >> 4) * 4;
#pragma unroll
    for (int j = 0; j < 4; ++j) {
        const int n = n0 + wn * 64 + j * 16 + col;
        const bool ok = (n < P_);
        const float bb1 = ok ? upb[n] : 0.f;
        const float bb2 = ok ? upb[P_ + n] : 0.f;
#pragma unroll
        for (int i = 0; i < 4; ++i)
#pragma unroll
            for (int r = 0; r < 4; ++r) {
                const int mm = m0 + wm * 64 + i * 16 + rb0 + r;
                float gval = 0.f;
                if (ok) {
                    const float u1 = acc1[i][j][r] + bb1;
                    const float u2 = acc2[i][j][r] + bb2;
                    const float ge = 0.5f * u2 * (1.f + erff(u2 * 0.70710678118654752f));
                    gval = u1 * ge;
                }
                G[(size_t)mm * PPAD_ + n] = f2b(gval);
            }
    }
}

// ---------------- down GEMM -> fp32 out with bias + residual ----------------
__global__ __launch_bounds__(256) void gemm_down_out(
    const u16* __restrict__ A, const u16* __restrict__ BT,
    const float* __restrict__ bias, const float* __restrict__ resid,
    float* __restrict__ C, int K, int ldc)
{
    v4f acc[4][4];
#pragma unroll
    for (int i = 0; i < 4; ++i)
#pragma unroll
        for (int j = 0; j < 4; ++j)
#pragma unroll
            for (int r = 0; r < 4; ++r) acc[i][j][r] = 0.f;
    const int m0 = blockIdx.y * 128, n0 = blockIdx.x * 128;
    gemm128_core(A, BT, K, m0, n0, acc);
    const int tid = threadIdx.x, wave = tid >> 6, lane = tid & 63;
    const int wm = wave & 1, wn = wave >> 1;
    const int col = lane & 15, rb0 = (lane >> 4) * 4;
#pragma unroll
    for (int j = 0; j < 4; ++j) {
        const int n = n0 + wn * 64 + j * 16 + col;
        const float bv = bias[n];
#pragma unroll
        for (int i = 0; i < 4; ++i)
#pragma unroll
            for (int r = 0; r < 4; ++r) {
                const int mm = m0 + wm * 64 + i * 16 + rb0 + r;
                C[(size_t)mm * ldc + n] = acc[i][j][r] + bv + resid[(size_t)mm * ldc + n];
            }
    }
}

// ============================ launcher ======================================
extern "C" void kernel_launch(void* const* d_in, const int* in_sizes, int n_in,
                              void* d_out, int out_size, void* d_ws, size_t ws_size,
                              hipStream_t stream)
{
    const float* x     = (const float*)d_in[0];
    const float* ln_w  = (const float*)d_in[1];
    const float* ln_b  = (const float*)d_in[2];
    const float* hln_w = (const float*)d_in[3];
    const float* hln_b = (const float*)d_in[4];
    const float* Wz = (const float*)d_in[5];  const float* bz  = (const float*)d_in[6];
    const float* Wi = (const float*)d_in[7];  const float* bi  = (const float*)d_in[8];
    const float* Wo = (const float*)d_in[9];  const float* bo  = (const float*)d_in[10];
    const float* Wf = (const float*)d_in[11]; const float* bfv = (const float*)d_in[12];
    const float* Rz = (const float*)d_in[13]; const float* rbz = (const float*)d_in[14];
    const float* Ri = (const float*)d_in[15]; const float* rbi = (const float*)d_in[16];
    const float* Ro = (const float*)d_in[17]; const float* rbo = (const float*)d_in[18];
    const float* Rf = (const float*)d_in[19]; const float* rbf = (const float*)d_in[20];
    const float* up_w   = (const float*)d_in[21]; const float* up_b   = (const float*)d_in[22];
    const float* down_w = (const float*)d_in[23]; const float* down_b = (const float*)d_in[24];
    float* out = (float*)d_out;

    // ---- workspace layout (adaptive to ws_size) ----
    size_t off = 0;
    char* base = (char*)d_ws;
    auto alloc = [&](size_t bytes) -> char* {
        char* r = base + off; off += (bytes + 255) & ~(size_t)255; return r;
    };
    u16*   WT4   = (u16*)  alloc((size_t)4 * H_ * D_ * 2);      // 8 MiB
    u16*   W1T   = (u16*)  alloc((size_t)PPAD_ * H_ * 2);       // 2.75 MiB
    u16*   W2T   = (u16*)  alloc((size_t)PPAD_ * H_ * 2);       // 2.75 MiB
    u16*   dnT   = (u16*)  alloc((size_t)D_ * PPAD_ * 2);       // 2.75 MiB
    u16*   RQ    = (u16*)  alloc((size_t)8 * 512 * 128 * 2);    // 1 MiB
    float* bias4 = (float*)alloc(4096 * 4);
    float* rb4   = (float*)alloc(4096 * 4);
    float* state = (float*)alloc((size_t)64 * 4 * 128 * 4);     // 128 KiB
    u16*   hbn   = (u16*)  alloc((size_t)M_ * H_ * 2);          // 32 MiB
    char*  dyn   = base + off;
    u16*   xnb   = (u16*)dyn;                                   // 32 MiB
    const size_t xnb_bytes = (size_t)M_ * H_ * 2;
    u16*   gbuf  = (u16*)dyn;  // overlays xnb+gx (both dead by up-GEMM time)

    // pick largest Tc whose gx chunk fits
    const size_t fixed = off + xnb_bytes;
    int Tc = 256;
    if      (ws_size >= fixed + (size_t)4 * B_ * 2048 * H_ * 2) Tc = 2048;
    else if (ws_size >= fixed + (size_t)4 * B_ * 1024 * H_ * 2) Tc = 1024;
    else if (ws_size >= fixed + (size_t)4 * B_ * 512  * H_ * 2) Tc = 512;
    u16* gx = (u16*)(dyn + xnb_bytes);
    const int NC = T_ / Tc;

    // ---- weight prep ----
    dim3 tb(32, 8);
    const float* Ws[4] = {Wz, Wi, Wo, Wf};
    for (int g = 0; g < 4; ++g)
        transpose_cast<<<dim3(32, 32), tb, 0, stream>>>(
            Ws[g], WT4 + (size_t)g * H_ * D_, D_, H_, D_, H_, H_);
    transpose_cast<<<dim3(44, 32), tb, 0, stream>>>(up_w,      W1T, H_, P_, H_, PPAD_, 2 * P_);
    transpose_cast<<<dim3(44, 32), tb, 0, stream>>>(up_w + P_, W2T, H_, P_, H_, PPAD_, 2 * P_);
    transpose_cast<<<dim3(32, 44), tb, 0, stream>>>(down_w, dnT, P_, D_, PPAD_, D_, D_);
    bias4_concat<<<16, 256, 0, stream>>>(bz, bi, bo, bfv, bias4);
    bias4_concat<<<16, 256, 0, stream>>>(rbz, rbi, rbo, rbf, rb4);
    rq_prep<<<dim3(512, 8), 128, 0, stream>>>(Rz, Ri, Ro, Rf, RQ);

    // ---- input LN ----
    ln_cast_kernel<<<M_, 256, 0, stream>>>(x, ln_w, ln_b, xnb);

    // ---- chunked gate GEMM + scan ----
    for (int cidx = 0; cidx < NC; ++cidx) {
        const int t0 = cidx * Tc;
        gemm_gate4<<<dim3(32, B_ * (Tc / 128)), 256, 0, stream>>>(
            xnb, WT4, bias4, gx, t0, Tc);
        scan_kernel<<<64, 512, 0, stream>>>(
            gx, RQ, rb4, state, hbn, t0, Tc, cidx == 0 ? 1 : 0);
    }

    // ---- multihead LN (in place) ----
    mln_kernel<<<M_, 512, 0, stream>>>(hbn, hln_w, hln_b, hbn);

    // ---- FFN ----
    gemm_up_geglu<<<dim3(PPAD_ / 128, 128), 256, 0, stream>>>(hbn, W1T, W2T, up_b, gbuf);
    gemm_down_out<<<dim3(8, 128), 256, 0, stream>>>(gbuf, dnT, down_b, x, out, PPAD_, D_);

    (void)in_sizes; (void)n_in; (void)out_size;
}